// Round 5
// baseline (3108.374 us; speedup 1.0000x reference)
//
#include <hip/hip_runtime.h>
#include <hip/hip_bf16.h>
#include <stdint.h>

// Autoregressive LSTM decode, B=4096, H=1024, A=128, 50 steps.
// steps>=1: x==h  =>  gates = h @ (w_ih+w_hh)^T + bias.
// Gates GEMM: 256^2-tile 8-phase schedule (T1+T2+T3+T4+T5), fused LSTM cell,
// c/bias prefetched into registers ahead of the staging pipeline.
// Pred GEMM: separate latency-optimized kernel (no LDS, direct-global MFMA).

#define B_SZ   4096
#define H_SZ   1024
#define A_SZ   128
#define NSTEP  50
#define NT     16      // K tiles of 64 (K = 1024)

using bf16 = __hip_bfloat16;
typedef __attribute__((ext_vector_type(8))) short bf16x8;   // 8 bf16 = 4 VGPR
typedef __attribute__((ext_vector_type(4))) float f32x4;    // MFMA C/D frag

__device__ __forceinline__ void gload_lds16(const void* g, void* l) {
    __builtin_amdgcn_global_load_lds(
        (const __attribute__((address_space(1))) unsigned int*)g,
        (__attribute__((address_space(3))) unsigned int*)l, 16, 0, 0);
}

#define FENCE() asm volatile("" ::: "memory")
#define BAR()   do { FENCE(); __builtin_amdgcn_s_barrier(); FENCE(); } while (0)
#define VMC6()  asm volatile("s_waitcnt vmcnt(6)" ::: "memory")
#define VMC0()  asm volatile("s_waitcnt vmcnt(0)" ::: "memory")
#define LGKM0() asm volatile("s_waitcnt lgkmcnt(0)" ::: "memory")

__device__ __forceinline__ float sigf(float x) {
    return 1.f / (1.f + __expf(-x));
}
__device__ __forceinline__ float tanh_(float x) {
    float e = __expf(-2.f * fabsf(x));
    float t = (1.f - e) / (1.f + e);
    return copysignf(t, x);
}

// ---------------- prep kernels (run once per launch) ----------------

__global__ void prep_weights(const float4* __restrict__ wih,
                             const float4* __restrict__ whh,
                             bf16* __restrict__ Wc, bf16* __restrict__ Wi) {
    int i = blockIdx.x * 256 + threadIdx.x;
    float4 a = wih[i], b = whh[i];
    bf16 tc[4] = {__float2bfloat16(a.x + b.x), __float2bfloat16(a.y + b.y),
                  __float2bfloat16(a.z + b.z), __float2bfloat16(a.w + b.w)};
    bf16 ti[4] = {__float2bfloat16(a.x), __float2bfloat16(a.y),
                  __float2bfloat16(a.z), __float2bfloat16(a.w)};
    *(uint64_t*)(Wc + 4 * (size_t)i) = *(const uint64_t*)tc;
    *(uint64_t*)(Wi + 4 * (size_t)i) = *(const uint64_t*)ti;
}

__global__ void prep_cast(const float4* __restrict__ in, bf16* __restrict__ out) {
    int i = blockIdx.x * 256 + threadIdx.x;
    float4 a = in[i];
    bf16 t[4] = {__float2bfloat16(a.x), __float2bfloat16(a.y),
                 __float2bfloat16(a.z), __float2bfloat16(a.w)};
    *(uint64_t*)(out + 4 * (size_t)i) = *(const uint64_t*)t;
}

__global__ void prep_bias(const float* __restrict__ a, const float* __restrict__ b,
                          float* __restrict__ o) {
    int i = blockIdx.x * 256 + threadIdx.x;
    o[i] = a[i] + b[i];
}

// ---------------- fused gates GEMM + LSTM cell ----------------
// grid: 256 blocks (1/CU, XCD-swizzled). Block: 256 batch rows x (4 gates x 64 j).
// 8 waves 2Mx4N; acc[8 m][4 gates]. LDS: A/B double-buffered, 128 KiB, swizzled.
// c/bias loads are issued BEFORE the prologue stages: they are older in vmcnt
// order, so the first VMC6 drains them and all in-loop counting is unchanged.

__global__ __launch_bounds__(512, 2)
void lstm_gates(const bf16* __restrict__ hin, const bf16* __restrict__ W,
                const float* __restrict__ bias, float* __restrict__ c,
                bf16* __restrict__ hout, int step0) {
    __shared__ __align__(16) bf16 sm[65536];          // 128 KiB
    bf16* const lA0 = sm;
    bf16* const lA1 = sm + 16384;
    bf16* const lB0 = sm + 32768;
    bf16* const lB1 = sm + 49152;

    const int tid    = threadIdx.x;
    const int w      = tid >> 6;
    const int lane   = tid & 63;
    const int wr     = w >> 2;
    const int wc     = w & 3;
    const int lane15 = lane & 15;
    const int lhi    = lane >> 4;

    const int bid     = blockIdx.x;
    const int logical = (bid & 7) * 32 + (bid >> 3);   // bijective XCD swizzle
    const int bm0     = (logical >> 4) * 256;
    const int j0      = (logical & 15) * 64;

    const int scolb = ((tid & 7) * 16) ^ (((tid >> 3) & 7) << 4);
    const char* baseA = (const char*)hin + (size_t)(bm0 + (tid >> 3)) * 2048 + scolb;
    const char* baseB = (const char*)W   + (size_t)(j0  + (tid >> 3)) * 2048 + scolb;

    const int cs0 = ((     lhi * 16) ^ ((lane & 7) << 4)) >> 1;
    const int cs1 = ((64 + lhi * 16) ^ ((lane & 7) << 4)) >> 1;
    const int rA  = (wr * 128 + lane15) * 64;
    const int rB  = (wc * 16  + lane15) * 64;

    // ---- prefetch c and bias into registers (oldest VMEM; drained by VMC6)
    const int jc = j0 + wc * 16 + lane15;
    const float bi  = bias[jc];
    const float bff = bias[H_SZ + jc];
    const float bg  = bias[2 * H_SZ + jc];
    const float bo  = bias[3 * H_SZ + jc];
    float cpre[8][4];
    if (!step0) {
#pragma unroll
        for (int m = 0; m < 8; ++m)
#pragma unroll
            for (int r = 0; r < 4; ++r)
                cpre[m][r] = c[(size_t)(bm0 + wr * 128 + m * 16 + lhi * 4 + r) * H_SZ + jc];
    } else {
#pragma unroll
        for (int m = 0; m < 8; ++m)
#pragma unroll
            for (int r = 0; r < 4; ++r) cpre[m][r] = 0.f;
    }

    f32x4 acc[8][4];
    const f32x4 z = {0.f, 0.f, 0.f, 0.f};
#pragma unroll
    for (int m = 0; m < 8; ++m)
#pragma unroll
        for (int n = 0; n < 4; ++n) acc[m][n] = z;

    auto SGA = [&](int t, int h) {
        bf16* dst = ((t & 1) ? lA1 : lA0) + h * 8192 + w * 512;
        const char* g = baseA + (size_t)(h * 128) * 2048 + (size_t)t * 128;
        gload_lds16(g, dst);
        gload_lds16(g + (size_t)64 * 2048, dst + 4096);
    };
    auto SGB = [&](int t, int h) {
        bf16* dst = ((t & 1) ? lB1 : lB0) + h * 8192 + w * 512;
        const char* g = baseB + (size_t)(h * 2) * 2097152 + (size_t)t * 128;
        gload_lds16(g, dst);
        gload_lds16(g + 2097152, dst + 4096);
    };

    // prologue: 7 half-tile stages (14 gload_lds)
    SGB(0, 0); SGB(0, 1); SGA(0, 0); SGA(0, 1);
    SGB(1, 0); SGB(1, 1); SGA(1, 0);

    VMC6();          // tile 0 landed; c/bias (older) fully drained
    BAR();

    for (int t = 0; t < NT; ++t) {
        const bf16* Ad = (t & 1) ? lA1 : lA0;
        const bf16* Bd = (t & 1) ? lB1 : lB0;
        bf16x8 av[4][2], bv[4][2];

        // phase 0: m0-3 x n0-1; stage A1(t+1)
#pragma unroll
        for (int m = 0; m < 4; ++m) {
            av[m][0] = *(const bf16x8*)(Ad + rA + m * 1024 + cs0);
            av[m][1] = *(const bf16x8*)(Ad + rA + m * 1024 + cs1);
        }
#pragma unroll
        for (int n = 0; n < 2; ++n) {
            bv[n][0] = *(const bf16x8*)(Bd + rB + n * 4096 + cs0);
            bv[n][1] = *(const bf16x8*)(Bd + rB + n * 4096 + cs1);
        }
        if (t + 1 < NT) SGA(t + 1, 1);
        BAR(); LGKM0();
        __builtin_amdgcn_s_setprio(1);
#pragma unroll
        for (int n = 0; n < 2; ++n)
#pragma unroll
            for (int m = 0; m < 4; ++m) {
                acc[m][n] = __builtin_amdgcn_mfma_f32_16x16x32_bf16(av[m][0], bv[n][0], acc[m][n], 0, 0, 0);
                acc[m][n] = __builtin_amdgcn_mfma_f32_16x16x32_bf16(av[m][1], bv[n][1], acc[m][n], 0, 0, 0);
            }
        __builtin_amdgcn_s_setprio(0);
        BAR();

        // phase 1: m0-3 x n2-3; stage B0(t+2)
#pragma unroll
        for (int n = 2; n < 4; ++n) {
            bv[n][0] = *(const bf16x8*)(Bd + rB + n * 4096 + cs0);
            bv[n][1] = *(const bf16x8*)(Bd + rB + n * 4096 + cs1);
        }
        if (t + 2 < NT) SGB(t + 2, 0);
        BAR(); LGKM0();
        __builtin_amdgcn_s_setprio(1);
#pragma unroll
        for (int n = 2; n < 4; ++n)
#pragma unroll
            for (int m = 0; m < 4; ++m) {
                acc[m][n] = __builtin_amdgcn_mfma_f32_16x16x32_bf16(av[m][0], bv[n][0], acc[m][n], 0, 0, 0);
                acc[m][n] = __builtin_amdgcn_mfma_f32_16x16x32_bf16(av[m][1], bv[n][1], acc[m][n], 0, 0, 0);
            }
        __builtin_amdgcn_s_setprio(0);
        BAR();

        // phase 2: m4-7 x n0-1; stage B1(t+2)
#pragma unroll
        for (int m = 0; m < 4; ++m) {
            av[m][0] = *(const bf16x8*)(Ad + rA + (m + 4) * 1024 + cs0);
            av[m][1] = *(const bf16x8*)(Ad + rA + (m + 4) * 1024 + cs1);
        }
        if (t + 2 < NT) SGB(t + 2, 1);
        BAR(); LGKM0();
        __builtin_amdgcn_s_setprio(1);
#pragma unroll
        for (int n = 0; n < 2; ++n)
#pragma unroll
            for (int m = 0; m < 4; ++m) {
                acc[m + 4][n] = __builtin_amdgcn_mfma_f32_16x16x32_bf16(av[m][0], bv[n][0], acc[m + 4][n], 0, 0, 0);
                acc[m + 4][n] = __builtin_amdgcn_mfma_f32_16x16x32_bf16(av[m][1], bv[n][1], acc[m + 4][n], 0, 0, 0);
            }
        __builtin_amdgcn_s_setprio(0);
        BAR();

        // phase 3: m4-7 x n2-3; stage A0(t+2)
        if (t + 2 < NT) SGA(t + 2, 0);
        BAR(); LGKM0();
        __builtin_amdgcn_s_setprio(1);
#pragma unroll
        for (int n = 2; n < 4; ++n)
#pragma unroll
            for (int m = 0; m < 4; ++m) {
                acc[m + 4][n] = __builtin_amdgcn_mfma_f32_16x16x32_bf16(av[m][0], bv[n][0], acc[m + 4][n], 0, 0, 0);
                acc[m + 4][n] = __builtin_amdgcn_mfma_f32_16x16x32_bf16(av[m][1], bv[n][1], acc[m + 4][n], 0, 0, 0);
            }
        __builtin_amdgcn_s_setprio(0);
        if (t < NT - 1) {
            if (t == NT - 2) { VMC0(); } else { VMC6(); }
        }
        BAR();
    }

    // ---- fused LSTM cell epilogue (i/f/g/o lane-local: n-frag == gate)
#pragma unroll
    for (int m = 0; m < 8; ++m) {
#pragma unroll
        for (int r = 0; r < 4; ++r) {
            int row = bm0 + wr * 128 + m * 16 + lhi * 4 + r;
            size_t idx = (size_t)row * H_SZ + jc;
            float iv = acc[m][0][r] + bi;
            float fv = acc[m][1][r] + bff;
            float gv = acc[m][2][r] + bg;
            float ov = acc[m][3][r] + bo;
            float cn = sigf(fv) * cpre[m][r] + sigf(iv) * tanh_(gv);
            float hn = sigf(ov) * tanh_(cn);
            c[idx] = cn;
            hout[idx] = __float2bfloat16(hn);
        }
    }
}

// ---------------- pred GEMM: out = h @ wp^T + bp ----------------
// Latency-optimized: no LDS, no barriers. 256 blocks x 8 waves; each wave
// computes one 16x16 output tile via 32 chained MFMAs on direct-global loads
// (wp is L2-resident: 256 KB, re-read by every block).

__global__ __launch_bounds__(512)
void pred_direct(const bf16* __restrict__ h, const bf16* __restrict__ wp,
                 const float* __restrict__ bp, float* __restrict__ out) {
    const int tid    = threadIdx.x;
    const int w      = tid >> 6;
    const int lane   = tid & 63;
    const int lane15 = lane & 15;
    const int lhi    = lane >> 4;
    const int pr0    = blockIdx.x * 16;

    const bf16* hp  = h  + (size_t)(pr0 + lane15) * H_SZ + lhi * 8;
    const bf16* wpp = wp + (size_t)(w * 16 + lane15) * H_SZ + lhi * 8;
    f32x4 pacc = {0.f, 0.f, 0.f, 0.f};
#pragma unroll 8
    for (int ks = 0; ks < 32; ++ks) {
        bf16x8 a = *(const bf16x8*)(hp + ks * 32);
        bf16x8 b = *(const bf16x8*)(wpp + ks * 32);
        pacc = __builtin_amdgcn_mfma_f32_16x16x32_bf16(a, b, pacc, 0, 0, 0);
    }
    const float bpv = bp[w * 16 + lane15];
    float* op = out + (size_t)(pr0 + lhi * 4) * A_SZ + w * 16 + lane15;
#pragma unroll
    for (int r = 0; r < 4; ++r) op[r * A_SZ] = pacc[r] + bpv;
}

// ---------------- launcher ----------------

extern "C" void kernel_launch(void* const* d_in, const int* in_sizes, int n_in,
                              void* d_out, int out_size, void* d_ws, size_t ws_size,
                              hipStream_t stream) {
    const float* enc   = (const float*)d_in[0];
    const float* wih   = (const float*)d_in[1];
    const float* whh   = (const float*)d_in[2];
    const float* bih   = (const float*)d_in[3];
    const float* bhh   = (const float*)d_in[4];
    const float* wpred = (const float*)d_in[5];
    const float* bpred = (const float*)d_in[6];
    float* out = (float*)d_out;

    char* ws = (char*)d_ws;
    const size_t WH = (size_t)4 * H_SZ * H_SZ;
    const size_t BH = (size_t)B_SZ * H_SZ;
    bf16*  Wc   = (bf16*)ws;                 ws += WH * 2;
    bf16*  Wi   = (bf16*)ws;                 ws += WH * 2;
    bf16*  h0   = (bf16*)ws;                 ws += BH * 2;
    bf16*  h1   = (bf16*)ws;                 ws += BH * 2;
    float* cbuf = (float*)ws;                ws += BH * 4;
    bf16*  wp   = (bf16*)ws;                 ws += (size_t)A_SZ * H_SZ * 2;
    float* bias = (float*)ws;                ws += 4 * H_SZ * 4;

    prep_weights<<<4096, 256, 0, stream>>>((const float4*)wih, (const float4*)whh, Wc, Wi);
    prep_cast<<<128, 256, 0, stream>>>((const float4*)wpred, wp);
    prep_bias<<<16, 256, 0, stream>>>(bih, bhh, bias);
    prep_cast<<<4096, 256, 0, stream>>>((const float4*)enc, h0);

    bf16* hbuf[2] = {h0, h1};
    for (int s = 0; s < NSTEP; ++s) {
        const bf16* hin = hbuf[s & 1];
        bf16* hout      = hbuf[(s + 1) & 1];
        lstm_gates<<<256, 512, 0, stream>>>(
            hin, (s == 0) ? Wi : Wc, bias, cbuf, hout, s == 0 ? 1 : 0);
        pred_direct<<<256, 512, 0, stream>>>(
            hout, wp, bpred, out + (size_t)s * (B_SZ * A_SZ));
    }
}

// Round 6
// 2936.523 us; speedup vs baseline: 1.0585x; 1.0585x over previous
//
#include <hip/hip_runtime.h>
#include <hip/hip_bf16.h>
#include <stdint.h>

// Autoregressive LSTM decode, B=4096, H=1024, A=128, 50 steps.
// steps>=1: x==h  =>  gates = h @ (w_ih+w_hh)^T + bias.
// Gates GEMM: 256^2-tile 8-phase schedule (round-2 proven structure, untouched).
// h history: each step writes a distinct slot of a 50-step ring; all 50
// prediction GEMMs are batched into ONE (204800 x 128 x 1024) GEMM at the end.
// Falls back to ping-pong + per-step pred if ws_size is too small.

#define B_SZ   4096
#define H_SZ   1024
#define A_SZ   128
#define NSTEP  50
#define NT     16      // K tiles of 64 (K = 1024)

using bf16 = __hip_bfloat16;
typedef __attribute__((ext_vector_type(8))) short bf16x8;   // 8 bf16 = 4 VGPR
typedef __attribute__((ext_vector_type(4))) float f32x4;    // MFMA C/D frag

__device__ __forceinline__ void gload_lds16(const void* g, void* l) {
    __builtin_amdgcn_global_load_lds(
        (const __attribute__((address_space(1))) unsigned int*)g,
        (__attribute__((address_space(3))) unsigned int*)l, 16, 0, 0);
}

#define FENCE() asm volatile("" ::: "memory")
#define BAR()   do { FENCE(); __builtin_amdgcn_s_barrier(); FENCE(); } while (0)
#define VMC6()  asm volatile("s_waitcnt vmcnt(6)" ::: "memory")
#define VMC0()  asm volatile("s_waitcnt vmcnt(0)" ::: "memory")
#define LGKM0() asm volatile("s_waitcnt lgkmcnt(0)" ::: "memory")

__device__ __forceinline__ float sigf(float x) {
    return 1.f / (1.f + __expf(-x));
}
__device__ __forceinline__ float tanh_(float x) {
    float e = __expf(-2.f * fabsf(x));
    float t = (1.f - e) / (1.f + e);
    return copysignf(t, x);
}

// ---------------- prep kernels (run once per launch) ----------------

__global__ void prep_weights(const float4* __restrict__ wih,
                             const float4* __restrict__ whh,
                             bf16* __restrict__ Wc, bf16* __restrict__ Wi) {
    int i = blockIdx.x * 256 + threadIdx.x;
    float4 a = wih[i], b = whh[i];
    bf16 tc[4] = {__float2bfloat16(a.x + b.x), __float2bfloat16(a.y + b.y),
                  __float2bfloat16(a.z + b.z), __float2bfloat16(a.w + b.w)};
    bf16 ti[4] = {__float2bfloat16(a.x), __float2bfloat16(a.y),
                  __float2bfloat16(a.z), __float2bfloat16(a.w)};
    *(uint64_t*)(Wc + 4 * (size_t)i) = *(const uint64_t*)tc;
    *(uint64_t*)(Wi + 4 * (size_t)i) = *(const uint64_t*)ti;
}

__global__ void prep_cast(const float4* __restrict__ in, bf16* __restrict__ out) {
    int i = blockIdx.x * 256 + threadIdx.x;
    float4 a = in[i];
    bf16 t[4] = {__float2bfloat16(a.x), __float2bfloat16(a.y),
                 __float2bfloat16(a.z), __float2bfloat16(a.w)};
    *(uint64_t*)(out + 4 * (size_t)i) = *(const uint64_t*)t;
}

__global__ void prep_bias(const float* __restrict__ a, const float* __restrict__ b,
                          float* __restrict__ o) {
    int i = blockIdx.x * 256 + threadIdx.x;
    o[i] = a[i] + b[i];
}

// ---------------- fused gates GEMM + LSTM cell (round-2 proven) ----------------
// grid: 256 blocks (1/CU, XCD-swizzled). Block: 256 batch rows x (4 gates x 64 j).
// 8 waves 2Mx4N; acc[8 m][4 gates]. LDS: A/B double-buffered, 128 KiB, swizzled.

__global__ __launch_bounds__(512, 2)
void lstm_gates(const bf16* __restrict__ hin, const bf16* __restrict__ W,
                const float* __restrict__ bias, float* __restrict__ c,
                bf16* __restrict__ hout, int step0) {
    __shared__ __align__(16) bf16 sm[65536];          // 128 KiB
    bf16* const lA0 = sm;
    bf16* const lA1 = sm + 16384;
    bf16* const lB0 = sm + 32768;
    bf16* const lB1 = sm + 49152;

    const int tid    = threadIdx.x;
    const int w      = tid >> 6;
    const int lane   = tid & 63;
    const int wr     = w >> 2;
    const int wc     = w & 3;
    const int lane15 = lane & 15;
    const int lhi    = lane >> 4;

    const int bid     = blockIdx.x;
    const int logical = (bid & 7) * 32 + (bid >> 3);   // bijective XCD swizzle
    const int bm0     = (logical >> 4) * 256;
    const int j0      = (logical & 15) * 64;

    const int scolb = ((tid & 7) * 16) ^ (((tid >> 3) & 7) << 4);
    const char* baseA = (const char*)hin + (size_t)(bm0 + (tid >> 3)) * 2048 + scolb;
    const char* baseB = (const char*)W   + (size_t)(j0  + (tid >> 3)) * 2048 + scolb;

    const int cs0 = ((     lhi * 16) ^ ((lane & 7) << 4)) >> 1;
    const int cs1 = ((64 + lhi * 16) ^ ((lane & 7) << 4)) >> 1;
    const int rA  = (wr * 128 + lane15) * 64;
    const int rB  = (wc * 16  + lane15) * 64;

    f32x4 acc[8][4];
    const f32x4 z = {0.f, 0.f, 0.f, 0.f};
#pragma unroll
    for (int m = 0; m < 8; ++m)
#pragma unroll
        for (int n = 0; n < 4; ++n) acc[m][n] = z;

    auto SGA = [&](int t, int h) {
        bf16* dst = ((t & 1) ? lA1 : lA0) + h * 8192 + w * 512;
        const char* g = baseA + (size_t)(h * 128) * 2048 + (size_t)t * 128;
        gload_lds16(g, dst);
        gload_lds16(g + (size_t)64 * 2048, dst + 4096);
    };
    auto SGB = [&](int t, int h) {
        bf16* dst = ((t & 1) ? lB1 : lB0) + h * 8192 + w * 512;
        const char* g = baseB + (size_t)(h * 2) * 2097152 + (size_t)t * 128;
        gload_lds16(g, dst);
        gload_lds16(g + 2097152, dst + 4096);
    };

    // prologue: 7 half-tile stages (14 gload_lds)
    SGB(0, 0); SGB(0, 1); SGA(0, 0); SGA(0, 1);
    SGB(1, 0); SGB(1, 1); SGA(1, 0);

    VMC6();
    BAR();

    for (int t = 0; t < NT; ++t) {
        const bf16* Ad = (t & 1) ? lA1 : lA0;
        const bf16* Bd = (t & 1) ? lB1 : lB0;
        bf16x8 av[4][2], bv[4][2];

        // phase 0: m0-3 x n0-1; stage A1(t+1)
#pragma unroll
        for (int m = 0; m < 4; ++m) {
            av[m][0] = *(const bf16x8*)(Ad + rA + m * 1024 + cs0);
            av[m][1] = *(const bf16x8*)(Ad + rA + m * 1024 + cs1);
        }
#pragma unroll
        for (int n = 0; n < 2; ++n) {
            bv[n][0] = *(const bf16x8*)(Bd + rB + n * 4096 + cs0);
            bv[n][1] = *(const bf16x8*)(Bd + rB + n * 4096 + cs1);
        }
        if (t + 1 < NT) SGA(t + 1, 1);
        BAR(); LGKM0();
        __builtin_amdgcn_s_setprio(1);
#pragma unroll
        for (int n = 0; n < 2; ++n)
#pragma unroll
            for (int m = 0; m < 4; ++m) {
                acc[m][n] = __builtin_amdgcn_mfma_f32_16x16x32_bf16(av[m][0], bv[n][0], acc[m][n], 0, 0, 0);
                acc[m][n] = __builtin_amdgcn_mfma_f32_16x16x32_bf16(av[m][1], bv[n][1], acc[m][n], 0, 0, 0);
            }
        __builtin_amdgcn_s_setprio(0);
        BAR();

        // phase 1: m0-3 x n2-3; stage B0(t+2)
#pragma unroll
        for (int n = 2; n < 4; ++n) {
            bv[n][0] = *(const bf16x8*)(Bd + rB + n * 4096 + cs0);
            bv[n][1] = *(const bf16x8*)(Bd + rB + n * 4096 + cs1);
        }
        if (t + 2 < NT) SGB(t + 2, 0);
        BAR(); LGKM0();
        __builtin_amdgcn_s_setprio(1);
#pragma unroll
        for (int n = 2; n < 4; ++n)
#pragma unroll
            for (int m = 0; m < 4; ++m) {
                acc[m][n] = __builtin_amdgcn_mfma_f32_16x16x32_bf16(av[m][0], bv[n][0], acc[m][n], 0, 0, 0);
                acc[m][n] = __builtin_amdgcn_mfma_f32_16x16x32_bf16(av[m][1], bv[n][1], acc[m][n], 0, 0, 0);
            }
        __builtin_amdgcn_s_setprio(0);
        BAR();

        // phase 2: m4-7 x n0-1; stage B1(t+2)
#pragma unroll
        for (int m = 0; m < 4; ++m) {
            av[m][0] = *(const bf16x8*)(Ad + rA + (m + 4) * 1024 + cs0);
            av[m][1] = *(const bf16x8*)(Ad + rA + (m + 4) * 1024 + cs1);
        }
        if (t + 2 < NT) SGB(t + 2, 1);
        BAR(); LGKM0();
        __builtin_amdgcn_s_setprio(1);
#pragma unroll
        for (int n = 0; n < 2; ++n)
#pragma unroll
            for (int m = 0; m < 4; ++m) {
                acc[m + 4][n] = __builtin_amdgcn_mfma_f32_16x16x32_bf16(av[m][0], bv[n][0], acc[m + 4][n], 0, 0, 0);
                acc[m + 4][n] = __builtin_amdgcn_mfma_f32_16x16x32_bf16(av[m][1], bv[n][1], acc[m + 4][n], 0, 0, 0);
            }
        __builtin_amdgcn_s_setprio(0);
        BAR();

        // phase 3: m4-7 x n2-3; stage A0(t+2)
        if (t + 2 < NT) SGA(t + 2, 0);
        BAR(); LGKM0();
        __builtin_amdgcn_s_setprio(1);
#pragma unroll
        for (int n = 2; n < 4; ++n)
#pragma unroll
            for (int m = 0; m < 4; ++m) {
                acc[m + 4][n] = __builtin_amdgcn_mfma_f32_16x16x32_bf16(av[m][0], bv[n][0], acc[m + 4][n], 0, 0, 0);
                acc[m + 4][n] = __builtin_amdgcn_mfma_f32_16x16x32_bf16(av[m][1], bv[n][1], acc[m + 4][n], 0, 0, 0);
            }
        __builtin_amdgcn_s_setprio(0);
        if (t < NT - 1) {
            if (t == NT - 2) { VMC0(); } else { VMC6(); }
        }
        BAR();
    }

    // ---- fused LSTM cell epilogue (i/f/g/o lane-local: n-frag == gate)
    const int jc = j0 + wc * 16 + lane15;
    const float bi  = bias[jc];
    const float bff = bias[H_SZ + jc];
    const float bg  = bias[2 * H_SZ + jc];
    const float bo  = bias[3 * H_SZ + jc];
#pragma unroll
    for (int m = 0; m < 8; ++m) {
#pragma unroll
        for (int r = 0; r < 4; ++r) {
            int row = bm0 + wr * 128 + m * 16 + lhi * 4 + r;
            size_t idx = (size_t)row * H_SZ + jc;
            float iv = acc[m][0][r] + bi;
            float fv = acc[m][1][r] + bff;
            float gv = acc[m][2][r] + bg;
            float ov = acc[m][3][r] + bo;
            float cp = step0 ? 0.f : c[idx];
            float cn = sigf(fv) * cp + sigf(iv) * tanh_(gv);
            float hn = sigf(ov) * tanh_(cn);
            c[idx] = cn;
            hout[idx] = __float2bfloat16(hn);
        }
    }
}

// ---------------- batched pred GEMM over the full h history ----------------
// out(204800 x 128) = hist(204800 x 1024) @ wp^T + bp.
// 800 blocks x 512 threads; block: 256 rows x 128 cols; 8 waves 2Mx4N
// (wave: 128 rows x 32 cols, acc[8][2]). LDS: A 2x32KB + B 2x16KB = 96 KiB,
// double-buffered 2-barrier loop (stage t+1 while computing t, vmcnt(0)/tile).

__global__ __launch_bounds__(512)
void pred_big(const bf16* __restrict__ h, const bf16* __restrict__ wp,
              const float* __restrict__ bp, float* __restrict__ out) {
    __shared__ __align__(16) bf16 sA[2][16384];     // 2 x 32 KB
    __shared__ __align__(16) bf16 sB[2][8192];      // 2 x 16 KB

    const int tid    = threadIdx.x;
    const int w      = tid >> 6;
    const int lane   = tid & 63;
    const int wr     = w >> 2;
    const int wc     = w & 3;
    const int lane15 = lane & 15;
    const int lhi    = lane >> 4;
    const int bm0    = blockIdx.x * 256;

    const int scolb = ((tid & 7) * 16) ^ (((tid >> 3) & 7) << 4);
    const char* baseA = (const char*)h  + (size_t)(bm0 + (tid >> 3)) * 2048 + scolb;
    const char* baseB = (const char*)wp + (size_t)(tid >> 3) * 2048 + scolb;

    const int cs0 = ((     lhi * 16) ^ ((lane & 7) << 4)) >> 1;
    const int cs1 = ((64 + lhi * 16) ^ ((lane & 7) << 4)) >> 1;
    const int rA  = (wr * 128 + lane15) * 64;
    const int rB  = (wc * 32  + lane15) * 64;

    f32x4 acc[8][2];
    const f32x4 z = {0.f, 0.f, 0.f, 0.f};
#pragma unroll
    for (int m = 0; m < 8; ++m) { acc[m][0] = z; acc[m][1] = z; }

    auto STAGE = [&](int t) {
        bf16* dA = sA[t & 1] + w * 512;
        bf16* dB = sB[t & 1] + w * 512;
        const char* gA = baseA + (size_t)t * 128;
        const char* gB = baseB + (size_t)t * 128;
#pragma unroll
        for (int q = 0; q < 4; ++q)
            gload_lds16(gA + (size_t)(q * 64) * 2048, dA + q * 4096);
#pragma unroll
        for (int q = 0; q < 2; ++q)
            gload_lds16(gB + (size_t)(q * 64) * 2048, dB + q * 4096);
    };

    STAGE(0);
    VMC0(); BAR();
    for (int t = 0; t < NT; ++t) {
        if (t + 1 < NT) STAGE(t + 1);
        const bf16* Ad = sA[t & 1];
        const bf16* Bd = sB[t & 1];
#pragma unroll
        for (int kk = 0; kk < 2; ++kk) {
            const int cs = kk ? cs1 : cs0;
            bf16x8 bv0 = *(const bf16x8*)(Bd + rB + cs);
            bf16x8 bv1 = *(const bf16x8*)(Bd + rB + 1024 + cs);
#pragma unroll
            for (int m = 0; m < 8; ++m) {
                bf16x8 av = *(const bf16x8*)(Ad + rA + m * 1024 + cs);
                acc[m][0] = __builtin_amdgcn_mfma_f32_16x16x32_bf16(av, bv0, acc[m][0], 0, 0, 0);
                acc[m][1] = __builtin_amdgcn_mfma_f32_16x16x32_bf16(av, bv1, acc[m][1], 0, 0, 0);
            }
        }
        VMC0(); BAR();
    }

    const float bp0 = bp[wc * 32 + lane15];
    const float bp1 = bp[wc * 32 + 16 + lane15];
#pragma unroll
    for (int m = 0; m < 8; ++m)
#pragma unroll
        for (int r = 0; r < 4; ++r) {
            size_t row = (size_t)bm0 + wr * 128 + m * 16 + lhi * 4 + r;
            float* op = out + row * A_SZ + wc * 32 + lane15;
            op[0]  = acc[m][0][r] + bp0;
            op[16] = acc[m][1][r] + bp1;
        }
}

// ---------------- fallback per-step pred (no-LDS direct) ----------------

__global__ __launch_bounds__(512)
void pred_direct(const bf16* __restrict__ h, const bf16* __restrict__ wp,
                 const float* __restrict__ bp, float* __restrict__ out) {
    const int tid    = threadIdx.x;
    const int w      = tid >> 6;
    const int lane   = tid & 63;
    const int lane15 = lane & 15;
    const int lhi    = lane >> 4;
    const int pr0    = blockIdx.x * 16;

    const bf16* hp  = h  + (size_t)(pr0 + lane15) * H_SZ + lhi * 8;
    const bf16* wpp = wp + (size_t)(w * 16 + lane15) * H_SZ + lhi * 8;
    f32x4 pacc = {0.f, 0.f, 0.f, 0.f};
#pragma unroll 8
    for (int ks = 0; ks < 32; ++ks) {
        bf16x8 a = *(const bf16x8*)(hp + ks * 32);
        bf16x8 b = *(const bf16x8*)(wpp + ks * 32);
        pacc = __builtin_amdgcn_mfma_f32_16x16x32_bf16(a, b, pacc, 0, 0, 0);
    }
    const float bpv = bp[w * 16 + lane15];
    float* op = out + (size_t)(pr0 + lhi * 4) * A_SZ + w * 16 + lane15;
#pragma unroll
    for (int r = 0; r < 4; ++r) op[r * A_SZ] = pacc[r] + bpv;
}

// ---------------- launcher ----------------

extern "C" void kernel_launch(void* const* d_in, const int* in_sizes, int n_in,
                              void* d_out, int out_size, void* d_ws, size_t ws_size,
                              hipStream_t stream) {
    const float* enc   = (const float*)d_in[0];
    const float* wih   = (const float*)d_in[1];
    const float* whh   = (const float*)d_in[2];
    const float* bih   = (const float*)d_in[3];
    const float* bhh   = (const float*)d_in[4];
    const float* wpred = (const float*)d_in[5];
    const float* bpred = (const float*)d_in[6];
    float* out = (float*)d_out;

    const size_t WH = (size_t)4 * H_SZ * H_SZ;     // elements of 4H x H
    const size_t BH = (size_t)B_SZ * H_SZ;         // elements of B x H

    // workspace needed for the batched-pred path (bytes):
    const size_t need_big = WH * 2 * 2              // Wc, Wi
                          + BH * 2                  // encb
                          + (size_t)NSTEP * BH * 2  // h history ring
                          + BH * 4                  // c
                          + (size_t)A_SZ * H_SZ * 2 // wp
                          + (size_t)4 * H_SZ * 4;   // bias

    char* ws = (char*)d_ws;
    bf16*  Wc = (bf16*)ws;  ws += WH * 2;
    bf16*  Wi = (bf16*)ws;  ws += WH * 2;

    prep_weights<<<4096, 256, 0, stream>>>((const float4*)wih, (const float4*)whh, Wc, Wi);

    if (ws_size >= need_big) {
        bf16*  encb = (bf16*)ws;  ws += BH * 2;
        bf16*  hist = (bf16*)ws;  ws += (size_t)NSTEP * BH * 2;
        float* cbuf = (float*)ws; ws += BH * 4;
        bf16*  wp   = (bf16*)ws;  ws += (size_t)A_SZ * H_SZ * 2;
        float* bias = (float*)ws; ws += 4 * H_SZ * 4;

        prep_cast<<<128, 256, 0, stream>>>((const float4*)wpred, wp);
        prep_bias<<<16, 256, 0, stream>>>(bih, bhh, bias);
        prep_cast<<<4096, 256, 0, stream>>>((const float4*)enc, encb);

        for (int s = 0; s < NSTEP; ++s) {
            const bf16* hin = (s == 0) ? encb : hist + (size_t)(s - 1) * BH;
            bf16* hout      = hist + (size_t)s * BH;
            lstm_gates<<<256, 512, 0, stream>>>(
                hin, (s == 0) ? Wi : Wc, bias, cbuf, hout, s == 0 ? 1 : 0);
        }
        // all 50 preds in one GEMM: (NSTEP*B) x A x H
        pred_big<<<(NSTEP * B_SZ) / 256, 512, 0, stream>>>(hist, wp, bpred, out);
    } else {
        bf16*  h0   = (bf16*)ws;  ws += BH * 2;
        bf16*  h1   = (bf16*)ws;  ws += BH * 2;
        float* cbuf = (float*)ws; ws += BH * 4;
        bf16*  wp   = (bf16*)ws;  ws += (size_t)A_SZ * H_SZ * 2;
        float* bias = (float*)ws; ws += 4 * H_SZ * 4;

        prep_cast<<<128, 256, 0, stream>>>((const float4*)wpred, wp);
        prep_bias<<<16, 256, 0, stream>>>(bih, bhh, bias);
        prep_cast<<<4096, 256, 0, stream>>>((const float4*)enc, h0);

        bf16* hbuf[2] = {h0, h1};
        for (int s = 0; s < NSTEP; ++s) {
            const bf16* hin = hbuf[s & 1];
            bf16* hout      = hbuf[(s + 1) & 1];
            lstm_gates<<<256, 512, 0, stream>>>(
                hin, (s == 0) ? Wi : Wc, bias, cbuf, hout, s == 0 ? 1 : 0);
            pred_direct<<<256, 512, 0, stream>>>(
                hout, wp, bpred, out + (size_t)s * (B_SZ * A_SZ));
        }
    }
}